// Round 1
// baseline (10425.130 us; speedup 1.0000x reference)
//
#include <hip/hip_runtime.h>
#include <stdint.h>

#define NN 50000
#define NE 800000
#define M_PAD 50048   // 391 * 128

typedef __attribute__((ext_vector_type(8))) short short8;
typedef __attribute__((ext_vector_type(4))) float f32x4;

static __device__ __forceinline__ float bf2f(unsigned short v) {
    union { unsigned u; float f; } c; c.u = ((unsigned)v) << 16; return c.f;
}
static __device__ __forceinline__ unsigned short f2bf(float f) {
    union { float f; unsigned u; } c; c.f = f;
    unsigned u = c.u;
    u += 0x7fffu + ((u >> 16) & 1u);   // RNE, inputs finite
    return (unsigned short)(u >> 16);
}

// ---------------- elementwise converters ----------------
__global__ void f32_to_bf16_k(const float* __restrict__ in, unsigned short* __restrict__ out, long n4) {
    long i = (long)blockIdx.x * 256 + threadIdx.x;
    if (i >= n4) return;
    float4 v = ((const float4*)in)[i];
    ushort4 o; o.x = f2bf(v.x); o.y = f2bf(v.y); o.z = f2bf(v.z); o.w = f2bf(v.w);
    ((ushort4*)out)[i] = o;
}
__global__ void bf16_to_f32_k(const unsigned short* __restrict__ in, float* __restrict__ out, long n4) {
    long i = (long)blockIdx.x * 256 + threadIdx.x;
    if (i >= n4) return;
    ushort4 v = ((const ushort4*)in)[i];
    float4 o; o.x = bf2f(v.x); o.y = bf2f(v.y); o.z = bf2f(v.z); o.w = bf2f(v.w);
    ((float4*)out)[i] = o;
}
__global__ void copy_f32_k(const float* __restrict__ in, float* __restrict__ out, long n4) {
    long i = (long)blockIdx.x * 256 + threadIdx.x;
    if (i >= n4) return;
    ((float4*)out)[i] = ((const float4*)in)[i];
}
// W (K x N f32) -> Wt (N x K bf16). i = n*K + k (k fast => coalesced writes).
__global__ void wt_k(const float* __restrict__ w, unsigned short* __restrict__ wt, int K, int N) {
    int i = blockIdx.x * 256 + threadIdx.x;
    if (i >= K * N) return;
    int k = i % K, n = i / K;
    wt[i] = f2bf(w[(long)k * N + n]);
}

// ---------------- edge scatter-add: agg[dst] += h[src] ----------------
// thread handles 4 features of one edge; agg pre-initialized to h (=> z = h + sum)
__global__ void scatter_add_k(const unsigned short* __restrict__ h, const int* __restrict__ ei,
                              float* __restrict__ agg, int D, int dshift) {
    long idx = (long)blockIdx.x * 256 + threadIdx.x;
    long e = idx >> dshift;
    if (e >= NE) return;
    int g4 = (int)(idx & ((1 << dshift) - 1)) * 4;
    int s = ei[e], d = ei[NE + e];
    ushort4 hv = *(const ushort4*)(h + (size_t)s * D + g4);
    float* ap = agg + (size_t)d * D + g4;
    unsafeAtomicAdd(ap + 0, bf2f(hv.x));
    unsafeAtomicAdd(ap + 1, bf2f(hv.y));
    unsafeAtomicAdd(ap + 2, bf2f(hv.z));
    unsafeAtomicAdd(ap + 3, bf2f(hv.w));
}

// ---------------- bf16 MFMA GEMM: C = A(MxK) * Bt(NxK)^T + bias ----------------
// MODE 0: outF = dot + bias                      (residual projection, f32)
// MODE 1: outH = bf16(relu(dot + bias))          (first MLP layer)
// MODE 2: outF = relu(relu(dot + bias) + outF)   (second MLP layer + residual, in place)
template <int K, int N, int MODE>
__global__ __launch_bounds__(256, 2)
void gemm_k(const unsigned short* __restrict__ A, const unsigned short* __restrict__ Bt,
            const float* __restrict__ bias, float* __restrict__ outF,
            unsigned short* __restrict__ outH, int M) {
    __shared__ unsigned short lA[128 * 64];
    __shared__ unsigned short lB[128 * 64];
    const int tid = threadIdx.x;
    const int lane = tid & 63;
    const int wid = tid >> 6;
    const int wm = wid & 1, wn = wid >> 1;
    const int l15 = lane & 15, quad = lane >> 4;
    const int m0 = blockIdx.y * 128;
    const int n0 = blockIdx.x * 128;
    const int c8 = tid & 7;

    f32x4 acc[4][4];
#pragma unroll
    for (int i = 0; i < 4; ++i)
#pragma unroll
        for (int j = 0; j < 4; ++j) acc[i][j] = (f32x4){0.f, 0.f, 0.f, 0.f};

    for (int k0 = 0; k0 < K; k0 += 64) {
        // stage 128x64 bf16 tiles; XOR-swizzle slot so frag ds_read_b128 is conflict-free
#pragma unroll
        for (int r = 0; r < 4; ++r) {
            int row = r * 32 + (tid >> 3);
            int slot = c8 ^ (row & 7);
            *(uint4*)&lA[(row * 8 + slot) * 8] =
                *(const uint4*)(A + (size_t)(m0 + row) * K + k0 + c8 * 8);
            *(uint4*)&lB[(row * 8 + slot) * 8] =
                *(const uint4*)(Bt + (size_t)(n0 + row) * K + k0 + c8 * 8);
        }
        __syncthreads();
#pragma unroll
        for (int kk = 0; kk < 2; ++kk) {
            short8 aF[4], bF[4];
#pragma unroll
            for (int i = 0; i < 4; ++i) {
                int ml = wm * 64 + i * 16 + l15;
                int kb = kk * 4 + quad;
                aF[i] = *(const short8*)&lA[(ml * 8 + (kb ^ (ml & 7))) * 8];
                int nl = wn * 64 + i * 16 + l15;
                bF[i] = *(const short8*)&lB[(nl * 8 + (kb ^ (nl & 7))) * 8];
            }
#pragma unroll
            for (int i = 0; i < 4; ++i)
#pragma unroll
                for (int j = 0; j < 4; ++j)
                    acc[i][j] = __builtin_amdgcn_mfma_f32_16x16x32_bf16(aF[i], bF[j], acc[i][j], 0, 0, 0);
        }
        __syncthreads();
    }

    // epilogue: C/D layout col=lane&15, row=quad*4+reg
#pragma unroll
    for (int i = 0; i < 4; ++i) {
#pragma unroll
        for (int j = 0; j < 4; ++j) {
            int col = n0 + wn * 64 + j * 16 + l15;
            float bv = bias[col];
#pragma unroll
            for (int r = 0; r < 4; ++r) {
                int row = m0 + wm * 64 + i * 16 + quad * 4 + r;
                if (row < M) {
                    size_t o = (size_t)row * N + col;
                    float v = acc[i][j][r] + bv;
                    if (MODE == 0) outF[o] = v;
                    else if (MODE == 1) outH[o] = f2bf(fmaxf(v, 0.f));
                    else {
                        float u = fmaxf(v, 0.f) + outF[o];
                        outF[o] = fmaxf(u, 0.f);
                    }
                }
            }
        }
    }
}

// ---------------- LayerNorm: one block per row ----------------
template <int D, bool BF16OUT>
__global__ __launch_bounds__(256)
void ln_k(const float* __restrict__ t, const float* __restrict__ g, const float* __restrict__ b,
          unsigned short* __restrict__ outH, float* __restrict__ outF) {
    constexpr int VPT = D / 256;
    const int row = blockIdx.x;
    const int tid = threadIdx.x;
    const float* tp = t + (size_t)row * D;
    float vals[VPT];
    float s = 0.f, ss = 0.f;
#pragma unroll
    for (int i = 0; i < VPT; ++i) {
        float v = tp[i * 256 + tid];
        vals[i] = v; s += v; ss += v * v;
    }
#pragma unroll
    for (int off = 32; off; off >>= 1) { s += __shfl_down(s, off); ss += __shfl_down(ss, off); }
    __shared__ float ps[4], pss[4];
    int lane = tid & 63, wv = tid >> 6;
    if (lane == 0) { ps[wv] = s; pss[wv] = ss; }
    __syncthreads();
    float st = ps[0] + ps[1] + ps[2] + ps[3];
    float sst = pss[0] + pss[1] + pss[2] + pss[3];
    float mean = st / D;
    float var = sst / D - mean * mean;
    float inv = rsqrtf(var + 1e-5f);
#pragma unroll
    for (int i = 0; i < VPT; ++i) {
        int c = i * 256 + tid;
        float o = (vals[i] - mean) * inv * g[c] + b[c];
        if (BF16OUT) outH[(size_t)row * D + c] = f2bf(o);
        else outF[(size_t)row * D + c] = o;
    }
}

static inline int cdiv(long a, long b) { return (int)((a + b - 1) / b); }

extern "C" void kernel_launch(void* const* d_in, const int* in_sizes, int n_in,
                              void* d_out, int out_size, void* d_ws, size_t ws_size,
                              hipStream_t stream) {
    const float* x   = (const float*)d_in[0];
    const int*   ei  = (const int*)  d_in[1];
    const float* w1a = (const float*)d_in[2],  *b1a = (const float*)d_in[3];
    const float* w1b = (const float*)d_in[4],  *b1b = (const float*)d_in[5];
    const float* w2a = (const float*)d_in[6],  *b2a = (const float*)d_in[7];
    const float* w2b = (const float*)d_in[8],  *b2b = (const float*)d_in[9];
    const float* w3a = (const float*)d_in[10], *b3a = (const float*)d_in[11];
    const float* w3b = (const float*)d_in[12], *b3b = (const float*)d_in[13];
    const float* rp1 = (const float*)d_in[14], *rp1b = (const float*)d_in[15];
    const float* rp2 = (const float*)d_in[16], *rp2b = (const float*)d_in[17];
    const float* rp3 = (const float*)d_in[18], *rp3b = (const float*)d_in[19];
    const float* g1 = (const float*)d_in[20], *be1 = (const float*)d_in[21];
    const float* g2 = (const float*)d_in[22], *be2 = (const float*)d_in[23];
    const float* g3 = (const float*)d_in[24], *be3 = (const float*)d_in[25];

    char* ws = (char*)d_ws;
    size_t off = 0;
    auto alloc = [&](size_t n) { char* p = ws + off; off += (n + 255) & ~(size_t)255; return p; };
    unsigned short* w1aT = (unsigned short*)alloc((size_t)128 * 256 * 2);
    unsigned short* w1bT = (unsigned short*)alloc((size_t)256 * 256 * 2);
    unsigned short* w2aT = (unsigned short*)alloc((size_t)256 * 512 * 2);
    unsigned short* w2bT = (unsigned short*)alloc((size_t)512 * 512 * 2);
    unsigned short* w3aT = (unsigned short*)alloc((size_t)512 * 1024 * 2);
    unsigned short* w3bT = (unsigned short*)alloc((size_t)1024 * 1024 * 2);
    unsigned short* rp1T = (unsigned short*)alloc((size_t)128 * 256 * 2);
    unsigned short* rp2T = (unsigned short*)alloc((size_t)256 * 512 * 2);
    unsigned short* rp3T = (unsigned short*)alloc((size_t)512 * 1024 * 2);
    unsigned short* hA  = (unsigned short*)alloc((size_t)M_PAD * 512 * 2);
    unsigned short* hB  = (unsigned short*)alloc((size_t)M_PAD * 512 * 2);
    unsigned short* zin = (unsigned short*)alloc((size_t)M_PAD * 512 * 2);
    unsigned short* z1  = (unsigned short*)alloc((size_t)M_PAD * 1024 * 2);
    float* resb = (float*)alloc((size_t)M_PAD * 1024 * 4);  // doubles as agg buffer
    (void)ws_size; (void)in_sizes; (void)n_in; (void)out_size;

    // weights -> bf16 transposed (N x K)
    wt_k<<<cdiv(128 * 256, 256), 256, 0, stream>>>(w1a, w1aT, 128, 256);
    wt_k<<<cdiv(256 * 256, 256), 256, 0, stream>>>(w1b, w1bT, 256, 256);
    wt_k<<<cdiv(256 * 512, 256), 256, 0, stream>>>(w2a, w2aT, 256, 512);
    wt_k<<<cdiv(512 * 512, 256), 256, 0, stream>>>(w2b, w2bT, 512, 512);
    wt_k<<<cdiv(512 * 1024, 256), 256, 0, stream>>>(w3a, w3aT, 512, 1024);
    wt_k<<<cdiv(1024 * 1024, 256), 256, 0, stream>>>(w3b, w3bT, 1024, 1024);
    wt_k<<<cdiv(128 * 256, 256), 256, 0, stream>>>(rp1, rp1T, 128, 256);
    wt_k<<<cdiv(256 * 512, 256), 256, 0, stream>>>(rp2, rp2T, 256, 512);
    wt_k<<<cdiv(512 * 1024, 256), 256, 0, stream>>>(rp3, rp3T, 512, 1024);

    // x -> bf16
    f32_to_bf16_k<<<cdiv((long)NN * 128 / 4, 256), 256, 0, stream>>>(x, hA, (long)NN * 128 / 4);

    // ---- block 1: Din=128, Dout=256, h = hA (bf16), h_f32 = x ----
    copy_f32_k<<<cdiv((long)NN * 128 / 4, 256), 256, 0, stream>>>(x, resb, (long)NN * 128 / 4);
    scatter_add_k<<<cdiv((long)NE * 32, 256), 256, 0, stream>>>(hA, ei, resb, 128, 5);
    f32_to_bf16_k<<<cdiv((long)NN * 128 / 4, 256), 256, 0, stream>>>(resb, zin, (long)NN * 128 / 4);
    gemm_k<128, 256, 1><<<dim3(2, 391), 256, 0, stream>>>(zin, w1aT, b1a, nullptr, z1, NN);
    gemm_k<128, 256, 0><<<dim3(2, 391), 256, 0, stream>>>(hA, rp1T, rp1b, resb, nullptr, NN);
    gemm_k<256, 256, 2><<<dim3(2, 391), 256, 0, stream>>>(z1, w1bT, b1b, resb, nullptr, NN);
    ln_k<256, true><<<NN, 256, 0, stream>>>(resb, g1, be1, hB, nullptr);

    // ---- block 2: Din=256, Dout=512, h = hB ----
    bf16_to_f32_k<<<cdiv((long)NN * 256 / 4, 256), 256, 0, stream>>>(hB, resb, (long)NN * 256 / 4);
    scatter_add_k<<<cdiv((long)NE * 64, 256), 256, 0, stream>>>(hB, ei, resb, 256, 6);
    f32_to_bf16_k<<<cdiv((long)NN * 256 / 4, 256), 256, 0, stream>>>(resb, zin, (long)NN * 256 / 4);
    gemm_k<256, 512, 1><<<dim3(4, 391), 256, 0, stream>>>(zin, w2aT, b2a, nullptr, z1, NN);
    gemm_k<256, 512, 0><<<dim3(4, 391), 256, 0, stream>>>(hB, rp2T, rp2b, resb, nullptr, NN);
    gemm_k<512, 512, 2><<<dim3(4, 391), 256, 0, stream>>>(z1, w2bT, b2b, resb, nullptr, NN);
    ln_k<512, true><<<NN, 256, 0, stream>>>(resb, g2, be2, hA, nullptr);

    // ---- block 3: Din=512, Dout=1024, h = hA ----
    bf16_to_f32_k<<<cdiv((long)NN * 512 / 4, 256), 256, 0, stream>>>(hA, resb, (long)NN * 512 / 4);
    scatter_add_k<<<cdiv((long)NE * 128, 256), 256, 0, stream>>>(hA, ei, resb, 512, 7);
    f32_to_bf16_k<<<cdiv((long)NN * 512 / 4, 256), 256, 0, stream>>>(resb, zin, (long)NN * 512 / 4);
    gemm_k<512, 1024, 1><<<dim3(8, 391), 256, 0, stream>>>(zin, w3aT, b3a, nullptr, z1, NN);
    gemm_k<512, 1024, 0><<<dim3(8, 391), 256, 0, stream>>>(hA, rp3T, rp3b, resb, nullptr, NN);
    gemm_k<1024, 1024, 2><<<dim3(8, 391), 256, 0, stream>>>(z1, w3bT, b3b, resb, nullptr, NN);
    ln_k<1024, false><<<NN, 256, 0, stream>>>(resb, g3, be3, nullptr, (float*)d_out);
}

// Round 2
// 1587.217 us; speedup vs baseline: 6.5682x; 6.5682x over previous
//
#include <hip/hip_runtime.h>
#include <stdint.h>

#define NN 50000
#define NE 800000
#define M_PAD 50048   // 391 * 128

typedef __attribute__((ext_vector_type(8))) short short8;
typedef __attribute__((ext_vector_type(4))) float f32x4;

static __device__ __forceinline__ float bf2f(unsigned short v) {
    union { unsigned u; float f; } c; c.u = ((unsigned)v) << 16; return c.f;
}
static __device__ __forceinline__ unsigned short f2bf(float f) {
    union { float f; unsigned u; } c; c.f = f;
    unsigned u = c.u;
    u += 0x7fffu + ((u >> 16) & 1u);   // RNE, inputs finite
    return (unsigned short)(u >> 16);
}

// ---------------- elementwise converters ----------------
__global__ void f32_to_bf16_k(const float* __restrict__ in, unsigned short* __restrict__ out, long n4) {
    long i = (long)blockIdx.x * 256 + threadIdx.x;
    if (i >= n4) return;
    float4 v = ((const float4*)in)[i];
    ushort4 o; o.x = f2bf(v.x); o.y = f2bf(v.y); o.z = f2bf(v.z); o.w = f2bf(v.w);
    ((ushort4*)out)[i] = o;
}
// W (K x N f32) -> Wt (N x K bf16). i = n*K + k (k fast => coalesced writes).
__global__ void wt_k(const float* __restrict__ w, unsigned short* __restrict__ wt, int K, int N) {
    int i = blockIdx.x * 256 + threadIdx.x;
    if (i >= K * N) return;
    int k = i % K, n = i / K;
    wt[i] = f2bf(w[(long)k * N + n]);
}

// ---------------- CSR build ----------------
__global__ void zero_k(int* __restrict__ p, int n) {
    int i = blockIdx.x * 256 + threadIdx.x;
    if (i < n) p[i] = 0;
}
__global__ void hist_k(const int* __restrict__ ei, int* __restrict__ deg) {
    int e = blockIdx.x * 256 + threadIdx.x;
    if (e >= NE) return;
    atomicAdd(&deg[ei[NE + e]], 1);
}
// single-block exclusive scan over deg[NN] -> row_ptr, cursor
__global__ __launch_bounds__(1024)
void scan_k(const int* __restrict__ deg, int* __restrict__ row_ptr, int* __restrict__ cursor) {
    constexpr int T = 1024, C = (NN + T - 1) / T;  // 49
    const int tid = threadIdx.x;
    const int base = tid * C;
    int s = 0;
#pragma unroll 4
    for (int i = 0; i < C; ++i) {
        int idx = base + i;
        if (idx < NN) s += deg[idx];
    }
    __shared__ int sm[T];
    sm[tid] = s;
    __syncthreads();
    for (int off = 1; off < T; off <<= 1) {
        int v = (tid >= off) ? sm[tid - off] : 0;
        __syncthreads();
        sm[tid] += v;
        __syncthreads();
    }
    int run = (tid == 0) ? 0 : sm[tid - 1];
#pragma unroll 4
    for (int i = 0; i < C; ++i) {
        int idx = base + i;
        if (idx < NN) {
            row_ptr[idx] = run;
            cursor[idx] = run;
            run += deg[idx];
        }
    }
}
__global__ void build_col_k(const int* __restrict__ ei, int* __restrict__ cursor, int* __restrict__ col) {
    int e = blockIdx.x * 256 + threadIdx.x;
    if (e >= NE) return;
    int d = ei[NE + e];
    int p = atomicAdd(&cursor[d], 1);
    col[p] = ei[e];
}

// ---------------- gather-aggregate: z[n] = h[n] + sum_{j->n} h[j], bf16 out ----------------
template <int V> struct VecT;
template <> struct VecT<2> { using T = unsigned int; };
template <> struct VecT<4> { using T = uint2; };
template <> struct VecT<8> { using T = uint4; };

template <int D>
__global__ __launch_bounds__(256)
void agg_gather_k(const unsigned short* __restrict__ h,
                  const int* __restrict__ row_ptr, const int* __restrict__ deg,
                  const int* __restrict__ col, unsigned short* __restrict__ z) {
    constexpr int V = D / 64;
    using VT = typename VecT<V>::T;
    union U { VT v; unsigned short s[V]; };
    const int node = blockIdx.x * 4 + (threadIdx.x >> 6);
    if (node >= NN) return;
    const int lane = threadIdx.x & 63;
    const size_t fb = (size_t)lane * V;

    float acc[V];
    {
        U b; b.v = *(const VT*)(h + (size_t)node * D + fb);
#pragma unroll
        for (int i = 0; i < V; ++i) acc[i] = bf2f(b.s[i]);
    }
    const int s = row_ptr[node];
    const int e = s + deg[node];
    int t = s;
    for (; t + 2 <= e; t += 2) {
        int s0 = col[t], s1 = col[t + 1];
        U a0, a1;
        a0.v = *(const VT*)(h + (size_t)s0 * D + fb);
        a1.v = *(const VT*)(h + (size_t)s1 * D + fb);
#pragma unroll
        for (int i = 0; i < V; ++i) acc[i] += bf2f(a0.s[i]);
#pragma unroll
        for (int i = 0; i < V; ++i) acc[i] += bf2f(a1.s[i]);
    }
    if (t < e) {
        U a; a.v = *(const VT*)(h + (size_t)col[t] * D + fb);
#pragma unroll
        for (int i = 0; i < V; ++i) acc[i] += bf2f(a.s[i]);
    }
    U o;
#pragma unroll
    for (int i = 0; i < V; ++i) o.s[i] = f2bf(acc[i]);
    *(VT*)(z + (size_t)node * D + fb) = o.v;
}

// ---------------- bf16 MFMA GEMM: C = A(MxK) * Bt(NxK)^T + bias ----------------
// MODE 0: outF = dot + bias                      (residual projection, f32)
// MODE 1: outH = bf16(relu(dot + bias))          (first MLP layer)
// MODE 2: outF = relu(relu(dot + bias) + outF)   (second MLP layer + residual, in place)
template <int K, int N, int MODE>
__global__ __launch_bounds__(256, 2)
void gemm_k(const unsigned short* __restrict__ A, const unsigned short* __restrict__ Bt,
            const float* __restrict__ bias, float* __restrict__ outF,
            unsigned short* __restrict__ outH, int M) {
    __shared__ unsigned short lA[128 * 64];
    __shared__ unsigned short lB[128 * 64];
    const int tid = threadIdx.x;
    const int lane = tid & 63;
    const int wid = tid >> 6;
    const int wm = wid & 1, wn = wid >> 1;
    const int l15 = lane & 15, quad = lane >> 4;
    const int m0 = blockIdx.y * 128;
    const int n0 = blockIdx.x * 128;
    const int c8 = tid & 7;

    f32x4 acc[4][4];
#pragma unroll
    for (int i = 0; i < 4; ++i)
#pragma unroll
        for (int j = 0; j < 4; ++j) acc[i][j] = (f32x4){0.f, 0.f, 0.f, 0.f};

    for (int k0 = 0; k0 < K; k0 += 64) {
#pragma unroll
        for (int r = 0; r < 4; ++r) {
            int row = r * 32 + (tid >> 3);
            int slot = c8 ^ (row & 7);
            *(uint4*)&lA[(row * 8 + slot) * 8] =
                *(const uint4*)(A + (size_t)(m0 + row) * K + k0 + c8 * 8);
            *(uint4*)&lB[(row * 8 + slot) * 8] =
                *(const uint4*)(Bt + (size_t)(n0 + row) * K + k0 + c8 * 8);
        }
        __syncthreads();
#pragma unroll
        for (int kk = 0; kk < 2; ++kk) {
            short8 aF[4], bF[4];
#pragma unroll
            for (int i = 0; i < 4; ++i) {
                int ml = wm * 64 + i * 16 + l15;
                int kb = kk * 4 + quad;
                aF[i] = *(const short8*)&lA[(ml * 8 + (kb ^ (ml & 7))) * 8];
                int nl = wn * 64 + i * 16 + l15;
                bF[i] = *(const short8*)&lB[(nl * 8 + (kb ^ (nl & 7))) * 8];
            }
#pragma unroll
            for (int i = 0; i < 4; ++i)
#pragma unroll
                for (int j = 0; j < 4; ++j)
                    acc[i][j] = __builtin_amdgcn_mfma_f32_16x16x32_bf16(aF[i], bF[j], acc[i][j], 0, 0, 0);
        }
        __syncthreads();
    }

#pragma unroll
    for (int i = 0; i < 4; ++i) {
#pragma unroll
        for (int j = 0; j < 4; ++j) {
            int col = n0 + wn * 64 + j * 16 + l15;
            float bv = bias[col];
#pragma unroll
            for (int r = 0; r < 4; ++r) {
                int row = m0 + wm * 64 + i * 16 + quad * 4 + r;
                if (row < M) {
                    size_t o = (size_t)row * N + col;
                    float v = acc[i][j][r] + bv;
                    if (MODE == 0) outF[o] = v;
                    else if (MODE == 1) outH[o] = f2bf(fmaxf(v, 0.f));
                    else {
                        float u = fmaxf(v, 0.f) + outF[o];
                        outF[o] = fmaxf(u, 0.f);
                    }
                }
            }
        }
    }
}

// ---------------- LayerNorm: one block per row ----------------
template <int D, bool BF16OUT>
__global__ __launch_bounds__(256)
void ln_k(const float* __restrict__ t, const float* __restrict__ g, const float* __restrict__ b,
          unsigned short* __restrict__ outH, float* __restrict__ outF) {
    constexpr int VPT = D / 256;
    const int row = blockIdx.x;
    const int tid = threadIdx.x;
    const float* tp = t + (size_t)row * D;
    float vals[VPT];
    float s = 0.f, ss = 0.f;
#pragma unroll
    for (int i = 0; i < VPT; ++i) {
        float v = tp[i * 256 + tid];
        vals[i] = v; s += v; ss += v * v;
    }
#pragma unroll
    for (int off = 32; off; off >>= 1) { s += __shfl_down(s, off); ss += __shfl_down(ss, off); }
    __shared__ float ps[4], pss[4];
    int lane = tid & 63, wv = tid >> 6;
    if (lane == 0) { ps[wv] = s; pss[wv] = ss; }
    __syncthreads();
    float st = ps[0] + ps[1] + ps[2] + ps[3];
    float sst = pss[0] + pss[1] + pss[2] + pss[3];
    float mean = st / D;
    float var = sst / D - mean * mean;
    float inv = rsqrtf(var + 1e-5f);
#pragma unroll
    for (int i = 0; i < VPT; ++i) {
        int c = i * 256 + tid;
        float o = (vals[i] - mean) * inv * g[c] + b[c];
        if (BF16OUT) outH[(size_t)row * D + c] = f2bf(o);
        else outF[(size_t)row * D + c] = o;
    }
}

static inline int cdiv(long a, long b) { return (int)((a + b - 1) / b); }

extern "C" void kernel_launch(void* const* d_in, const int* in_sizes, int n_in,
                              void* d_out, int out_size, void* d_ws, size_t ws_size,
                              hipStream_t stream) {
    const float* x   = (const float*)d_in[0];
    const int*   ei  = (const int*)  d_in[1];
    const float* w1a = (const float*)d_in[2],  *b1a = (const float*)d_in[3];
    const float* w1b = (const float*)d_in[4],  *b1b = (const float*)d_in[5];
    const float* w2a = (const float*)d_in[6],  *b2a = (const float*)d_in[7];
    const float* w2b = (const float*)d_in[8],  *b2b = (const float*)d_in[9];
    const float* w3a = (const float*)d_in[10], *b3a = (const float*)d_in[11];
    const float* w3b = (const float*)d_in[12], *b3b = (const float*)d_in[13];
    const float* rp1 = (const float*)d_in[14], *rp1b = (const float*)d_in[15];
    const float* rp2 = (const float*)d_in[16], *rp2b = (const float*)d_in[17];
    const float* rp3 = (const float*)d_in[18], *rp3b = (const float*)d_in[19];
    const float* g1 = (const float*)d_in[20], *be1 = (const float*)d_in[21];
    const float* g2 = (const float*)d_in[22], *be2 = (const float*)d_in[23];
    const float* g3 = (const float*)d_in[24], *be3 = (const float*)d_in[25];

    char* ws = (char*)d_ws;
    size_t off = 0;
    auto alloc = [&](size_t n) { char* p = ws + off; off += (n + 255) & ~(size_t)255; return p; };
    unsigned short* w1aT = (unsigned short*)alloc((size_t)128 * 256 * 2);
    unsigned short* w1bT = (unsigned short*)alloc((size_t)256 * 256 * 2);
    unsigned short* w2aT = (unsigned short*)alloc((size_t)256 * 512 * 2);
    unsigned short* w2bT = (unsigned short*)alloc((size_t)512 * 512 * 2);
    unsigned short* w3aT = (unsigned short*)alloc((size_t)512 * 1024 * 2);
    unsigned short* w3bT = (unsigned short*)alloc((size_t)1024 * 1024 * 2);
    unsigned short* rp1T = (unsigned short*)alloc((size_t)128 * 256 * 2);
    unsigned short* rp2T = (unsigned short*)alloc((size_t)256 * 512 * 2);
    unsigned short* rp3T = (unsigned short*)alloc((size_t)512 * 1024 * 2);
    unsigned short* hA  = (unsigned short*)alloc((size_t)M_PAD * 512 * 2);
    unsigned short* hB  = (unsigned short*)alloc((size_t)M_PAD * 512 * 2);
    unsigned short* zin = (unsigned short*)alloc((size_t)M_PAD * 512 * 2);
    unsigned short* z1  = (unsigned short*)alloc((size_t)M_PAD * 1024 * 2);
    float* resb = (float*)alloc((size_t)M_PAD * 1024 * 4);
    int* deg     = (int*)alloc((size_t)NN * 4);
    int* row_ptr = (int*)alloc((size_t)NN * 4);
    int* cursor  = (int*)alloc((size_t)NN * 4);
    int* colv    = (int*)alloc((size_t)NE * 4);
    (void)ws_size; (void)in_sizes; (void)n_in; (void)out_size;

    // ---- CSR build (shared by all 3 blocks) ----
    zero_k<<<cdiv(NN, 256), 256, 0, stream>>>(deg, NN);
    hist_k<<<cdiv(NE, 256), 256, 0, stream>>>(ei, deg);
    scan_k<<<1, 1024, 0, stream>>>(deg, row_ptr, cursor);
    build_col_k<<<cdiv(NE, 256), 256, 0, stream>>>(ei, cursor, colv);

    // ---- weights -> bf16 transposed (N x K) ----
    wt_k<<<cdiv(128 * 256, 256), 256, 0, stream>>>(w1a, w1aT, 128, 256);
    wt_k<<<cdiv(256 * 256, 256), 256, 0, stream>>>(w1b, w1bT, 256, 256);
    wt_k<<<cdiv(256 * 512, 256), 256, 0, stream>>>(w2a, w2aT, 256, 512);
    wt_k<<<cdiv(512 * 512, 256), 256, 0, stream>>>(w2b, w2bT, 512, 512);
    wt_k<<<cdiv(512 * 1024, 256), 256, 0, stream>>>(w3a, w3aT, 512, 1024);
    wt_k<<<cdiv(1024 * 1024, 256), 256, 0, stream>>>(w3b, w3bT, 1024, 1024);
    wt_k<<<cdiv(128 * 256, 256), 256, 0, stream>>>(rp1, rp1T, 128, 256);
    wt_k<<<cdiv(256 * 512, 256), 256, 0, stream>>>(rp2, rp2T, 256, 512);
    wt_k<<<cdiv(512 * 1024, 256), 256, 0, stream>>>(rp3, rp3T, 512, 1024);

    // x -> bf16
    f32_to_bf16_k<<<cdiv((long)NN * 128 / 4, 256), 256, 0, stream>>>(x, hA, (long)NN * 128 / 4);

    // ---- block 1: Din=128, Dout=256, h = hA ----
    agg_gather_k<128><<<cdiv(NN, 4), 256, 0, stream>>>(hA, row_ptr, deg, colv, zin);
    gemm_k<128, 256, 1><<<dim3(2, 391), 256, 0, stream>>>(zin, w1aT, b1a, nullptr, z1, NN);
    gemm_k<128, 256, 0><<<dim3(2, 391), 256, 0, stream>>>(hA, rp1T, rp1b, resb, nullptr, NN);
    gemm_k<256, 256, 2><<<dim3(2, 391), 256, 0, stream>>>(z1, w1bT, b1b, resb, nullptr, NN);
    ln_k<256, true><<<NN, 256, 0, stream>>>(resb, g1, be1, hB, nullptr);

    // ---- block 2: Din=256, Dout=512, h = hB ----
    agg_gather_k<256><<<cdiv(NN, 4), 256, 0, stream>>>(hB, row_ptr, deg, colv, zin);
    gemm_k<256, 512, 1><<<dim3(4, 391), 256, 0, stream>>>(zin, w2aT, b2a, nullptr, z1, NN);
    gemm_k<256, 512, 0><<<dim3(4, 391), 256, 0, stream>>>(hB, rp2T, rp2b, resb, nullptr, NN);
    gemm_k<512, 512, 2><<<dim3(4, 391), 256, 0, stream>>>(z1, w2bT, b2b, resb, nullptr, NN);
    ln_k<512, true><<<NN, 256, 0, stream>>>(resb, g2, be2, hA, nullptr);

    // ---- block 3: Din=512, Dout=1024, h = hA ----
    agg_gather_k<512><<<cdiv(NN, 4), 256, 0, stream>>>(hA, row_ptr, deg, colv, zin);
    gemm_k<512, 1024, 1><<<dim3(8, 391), 256, 0, stream>>>(zin, w3aT, b3a, nullptr, z1, NN);
    gemm_k<512, 1024, 0><<<dim3(8, 391), 256, 0, stream>>>(hA, rp3T, rp3b, resb, nullptr, NN);
    gemm_k<1024, 1024, 2><<<dim3(8, 391), 256, 0, stream>>>(z1, w3bT, b3b, resb, nullptr, NN);
    ln_k<1024, false><<<NN, 256, 0, stream>>>(resb, g3, be3, nullptr, (float*)d_out);
}

// Round 3
// 1314.602 us; speedup vs baseline: 7.9303x; 1.2074x over previous
//
#include <hip/hip_runtime.h>
#include <stdint.h>

#define NN 50000
#define NE 800000
#define M_PAD 50048   // 391 * 128

typedef __attribute__((ext_vector_type(8))) short short8;
typedef __attribute__((ext_vector_type(4))) float f32x4;

static __device__ __forceinline__ float bf2f(unsigned short v) {
    union { unsigned u; float f; } c; c.u = ((unsigned)v) << 16; return c.f;
}
static __device__ __forceinline__ unsigned short f2bf(float f) {
    union { float f; unsigned u; } c; c.f = f;
    unsigned u = c.u;
    u += 0x7fffu + ((u >> 16) & 1u);   // RNE, inputs finite
    return (unsigned short)(u >> 16);
}

// ---------------- elementwise converters ----------------
__global__ void f32_to_bf16_k(const float* __restrict__ in, unsigned short* __restrict__ out, long n4) {
    long i = (long)blockIdx.x * 256 + threadIdx.x;
    if (i >= n4) return;
    float4 v = ((const float4*)in)[i];
    ushort4 o; o.x = f2bf(v.x); o.y = f2bf(v.y); o.z = f2bf(v.z); o.w = f2bf(v.w);
    ((ushort4*)out)[i] = o;
}
// W (K x N f32) -> Wt (N x K bf16). i = n*K + k (k fast => coalesced writes).
__global__ void wt_k(const float* __restrict__ w, unsigned short* __restrict__ wt, int K, int N) {
    int i = blockIdx.x * 256 + threadIdx.x;
    if (i >= K * N) return;
    int k = i % K, n = i / K;
    wt[i] = f2bf(w[(long)k * N + n]);
}

// ---------------- CSR build ----------------
__global__ void zero_k(int* __restrict__ p, int n) {
    int i = blockIdx.x * 256 + threadIdx.x;
    if (i < n) p[i] = 0;
}
__global__ void hist_k(const int* __restrict__ ei, int* __restrict__ deg) {
    int e = blockIdx.x * 256 + threadIdx.x;
    if (e >= NE) return;
    atomicAdd(&deg[ei[NE + e]], 1);
}
// single-block exclusive scan over deg[NN] -> row_ptr, cursor
__global__ __launch_bounds__(1024)
void scan_k(const int* __restrict__ deg, int* __restrict__ row_ptr, int* __restrict__ cursor) {
    constexpr int T = 1024, C = (NN + T - 1) / T;  // 49
    const int tid = threadIdx.x;
    const int base = tid * C;
    int s = 0;
#pragma unroll 4
    for (int i = 0; i < C; ++i) {
        int idx = base + i;
        if (idx < NN) s += deg[idx];
    }
    __shared__ int sm[T];
    sm[tid] = s;
    __syncthreads();
    for (int off = 1; off < T; off <<= 1) {
        int v = (tid >= off) ? sm[tid - off] : 0;
        __syncthreads();
        sm[tid] += v;
        __syncthreads();
    }
    int run = (tid == 0) ? 0 : sm[tid - 1];
#pragma unroll 4
    for (int i = 0; i < C; ++i) {
        int idx = base + i;
        if (idx < NN) {
            row_ptr[idx] = run;
            cursor[idx] = run;
            run += deg[idx];
        }
    }
}
__global__ void build_col_k(const int* __restrict__ ei, int* __restrict__ cursor, int* __restrict__ col) {
    int e = blockIdx.x * 256 + threadIdx.x;
    if (e >= NE) return;
    int d = ei[NE + e];
    int p = atomicAdd(&cursor[d], 1);
    col[p] = ei[e];
}

// ---------------- gather-aggregate: z[n] = h[n] + sum_{j->n} h[j], bf16 out ----------------
template <int V> struct VecT;
template <> struct VecT<2> { using T = unsigned int; };
template <> struct VecT<4> { using T = uint2; };
template <> struct VecT<8> { using T = uint4; };

template <int D>
__global__ __launch_bounds__(256)
void agg_gather_k(const unsigned short* __restrict__ h,
                  const int* __restrict__ row_ptr, const int* __restrict__ deg,
                  const int* __restrict__ col, unsigned short* __restrict__ z) {
    constexpr int V = D / 64;
    using VT = typename VecT<V>::T;
    union U { VT v; unsigned short s[V]; };
    const int node = blockIdx.x * 4 + (threadIdx.x >> 6);
    if (node >= NN) return;
    const int lane = threadIdx.x & 63;
    const size_t fb = (size_t)lane * V;

    float acc[V];
    {
        U b; b.v = *(const VT*)(h + (size_t)node * D + fb);
#pragma unroll
        for (int i = 0; i < V; ++i) acc[i] = bf2f(b.s[i]);
    }
    const int s = row_ptr[node];
    const int e = s + deg[node];
    int t = s;
    for (; t + 2 <= e; t += 2) {
        int s0 = col[t], s1 = col[t + 1];
        U a0, a1;
        a0.v = *(const VT*)(h + (size_t)s0 * D + fb);
        a1.v = *(const VT*)(h + (size_t)s1 * D + fb);
#pragma unroll
        for (int i = 0; i < V; ++i) acc[i] += bf2f(a0.s[i]);
#pragma unroll
        for (int i = 0; i < V; ++i) acc[i] += bf2f(a1.s[i]);
    }
    if (t < e) {
        U a; a.v = *(const VT*)(h + (size_t)col[t] * D + fb);
#pragma unroll
        for (int i = 0; i < V; ++i) acc[i] += bf2f(a.s[i]);
    }
    U o;
#pragma unroll
    for (int i = 0; i < V; ++i) o.s[i] = f2bf(acc[i]);
    *(VT*)(z + (size_t)node * D + fb) = o.v;
}

// ---------------- MFMA GEMM building blocks ----------------
// Stage a 128x64 bf16 tile (row stride = rstride shorts) into LDS via DMA.
// XOR swizzle is folded into the per-lane SOURCE address: LDS slot s of row r
// holds k-block (s ^ (r&7)), matching the fragment-read addressing below.
static __device__ __forceinline__ void stage_tile128x64(
    const unsigned short* __restrict__ src, size_t rstride,
    unsigned short* lds, int wid, int lane) {
#pragma unroll
    for (int r = 0; r < 4; ++r) {
        const int rows8 = wid * 32 + r * 8;
        const int row = rows8 + (lane >> 3);
        const int kblk = (lane & 7) ^ (row & 7);
        __builtin_amdgcn_global_load_lds(
            (const __attribute__((address_space(1))) void*)(src + (size_t)row * rstride + (size_t)kblk * 8),
            (__attribute__((address_space(3))) void*)(lds + rows8 * 64),
            16, 0, 0);
    }
}

#define GEMM_IDS                                   \
    const int tid = threadIdx.x;                   \
    const int lane = tid & 63;                     \
    const int wid = tid >> 6;                      \
    const int wm = wid & 1, wn = wid >> 1;         \
    const int l15 = lane & 15, quad = lane >> 4;   \
    const int m0 = blockIdx.y * 128;               \
    const int n0 = blockIdx.x * 128;

#define GEMM_KSTEP(AP, BP, KS)                                                        \
    for (int k0 = 0; k0 < (KS); k0 += 64) {                                           \
        stage_tile128x64((AP) + (size_t)m0 * (KS) + k0, (KS), lA, wid, lane);         \
        stage_tile128x64((BP) + (size_t)n0 * (KS) + k0, (KS), lB, wid, lane);         \
        __syncthreads();                                                              \
        _Pragma("unroll")                                                             \
        for (int kk = 0; kk < 2; ++kk) {                                              \
            short8 aF[4], bF[4];                                                      \
            _Pragma("unroll")                                                         \
            for (int i = 0; i < 4; ++i) {                                             \
                int ml = wm * 64 + i * 16 + l15;                                      \
                int kb = kk * 4 + quad;                                               \
                aF[i] = *(const short8*)&lA[(ml * 8 + (kb ^ (ml & 7))) * 8];          \
                int nl = wn * 64 + i * 16 + l15;                                      \
                bF[i] = *(const short8*)&lB[(nl * 8 + (kb ^ (nl & 7))) * 8];          \
            }                                                                         \
            _Pragma("unroll")                                                         \
            for (int i = 0; i < 4; ++i)                                               \
                _Pragma("unroll")                                                     \
                for (int j = 0; j < 4; ++j)                                           \
                    acc[i][j] = __builtin_amdgcn_mfma_f32_16x16x32_bf16(              \
                        aF[i], bF[j], acc[i][j], 0, 0, 0);                            \
        }                                                                             \
        __syncthreads();                                                              \
    }

// C = bf16(relu(A(MxK) * Bt(NxK)^T + bias))  -- first MLP layer
template <int K, int N>
__global__ __launch_bounds__(256, 2)
void gemm_relu_k(const unsigned short* __restrict__ A, const unsigned short* __restrict__ Bt,
                 const float* __restrict__ bias, unsigned short* __restrict__ outH, int M) {
    __shared__ unsigned short lA[128 * 64];
    __shared__ unsigned short lB[128 * 64];
    GEMM_IDS
    f32x4 acc[4][4];
#pragma unroll
    for (int i = 0; i < 4; ++i)
#pragma unroll
        for (int j = 0; j < 4; ++j) acc[i][j] = (f32x4){0.f, 0.f, 0.f, 0.f};

    GEMM_KSTEP(A, Bt, K)

#pragma unroll
    for (int i = 0; i < 4; ++i) {
#pragma unroll
        for (int j = 0; j < 4; ++j) {
            int col = n0 + wn * 64 + j * 16 + l15;
            float bv = bias[col];
#pragma unroll
            for (int r = 0; r < 4; ++r) {
                int row = m0 + wm * 64 + i * 16 + quad * 4 + r;
                if (row < M)
                    outH[(size_t)row * N + col] = f2bf(fmaxf(acc[i][j][r] + bv, 0.f));
            }
        }
    }
}

// outF = relu( relu(A1*B1t^T + b1) + A2*B2t^T + b2 )  -- 2nd MLP layer + residual proj fused
template <int K1, int K2, int N>
__global__ __launch_bounds__(256, 2)
void gemm_fused_k(const unsigned short* __restrict__ A1, const unsigned short* __restrict__ B1t,
                  const float* __restrict__ b1,
                  const unsigned short* __restrict__ A2, const unsigned short* __restrict__ B2t,
                  const float* __restrict__ b2,
                  float* __restrict__ outF, int M) {
    __shared__ unsigned short lA[128 * 64];
    __shared__ unsigned short lB[128 * 64];
    GEMM_IDS
    f32x4 acc[4][4];
#pragma unroll
    for (int i = 0; i < 4; ++i)
#pragma unroll
        for (int j = 0; j < 4; ++j) acc[i][j] = (f32x4){0.f, 0.f, 0.f, 0.f};

    GEMM_KSTEP(A1, B1t, K1)

    // in-register: acc = relu(acc + b1[col]); MFMA then keeps accumulating additively
#pragma unroll
    for (int j = 0; j < 4; ++j) {
        float bv = b1[n0 + wn * 64 + j * 16 + l15];
#pragma unroll
        for (int i = 0; i < 4; ++i)
#pragma unroll
            for (int r = 0; r < 4; ++r)
                acc[i][j][r] = fmaxf(acc[i][j][r] + bv, 0.f);
    }

    GEMM_KSTEP(A2, B2t, K2)

#pragma unroll
    for (int i = 0; i < 4; ++i) {
#pragma unroll
        for (int j = 0; j < 4; ++j) {
            int col = n0 + wn * 64 + j * 16 + l15;
            float bv = b2[col];
#pragma unroll
            for (int r = 0; r < 4; ++r) {
                int row = m0 + wm * 64 + i * 16 + quad * 4 + r;
                if (row < M)
                    outF[(size_t)row * N + col] = fmaxf(acc[i][j][r] + bv, 0.f);
            }
        }
    }
}

// ---------------- LayerNorm: one block per row ----------------
template <int D, bool BF16OUT>
__global__ __launch_bounds__(256)
void ln_k(const float* __restrict__ t, const float* __restrict__ g, const float* __restrict__ b,
          unsigned short* __restrict__ outH, float* __restrict__ outF) {
    constexpr int VPT = D / 256;
    const int row = blockIdx.x;
    const int tid = threadIdx.x;
    const float* tp = t + (size_t)row * D;
    float vals[VPT];
    float s = 0.f, ss = 0.f;
#pragma unroll
    for (int i = 0; i < VPT; ++i) {
        float v = tp[i * 256 + tid];
        vals[i] = v; s += v; ss += v * v;
    }
#pragma unroll
    for (int off = 32; off; off >>= 1) { s += __shfl_down(s, off); ss += __shfl_down(ss, off); }
    __shared__ float ps[4], pss[4];
    int lane = tid & 63, wv = tid >> 6;
    if (lane == 0) { ps[wv] = s; pss[wv] = ss; }
    __syncthreads();
    float st = ps[0] + ps[1] + ps[2] + ps[3];
    float sst = pss[0] + pss[1] + pss[2] + pss[3];
    float mean = st / D;
    float var = sst / D - mean * mean;
    float inv = rsqrtf(var + 1e-5f);
#pragma unroll
    for (int i = 0; i < VPT; ++i) {
        int c = i * 256 + tid;
        float o = (vals[i] - mean) * inv * g[c] + b[c];
        if (BF16OUT) outH[(size_t)row * D + c] = f2bf(o);
        else outF[(size_t)row * D + c] = o;
    }
}

static inline int cdiv(long a, long b) { return (int)((a + b - 1) / b); }

extern "C" void kernel_launch(void* const* d_in, const int* in_sizes, int n_in,
                              void* d_out, int out_size, void* d_ws, size_t ws_size,
                              hipStream_t stream) {
    const float* x   = (const float*)d_in[0];
    const int*   ei  = (const int*)  d_in[1];
    const float* w1a = (const float*)d_in[2],  *b1a = (const float*)d_in[3];
    const float* w1b = (const float*)d_in[4],  *b1b = (const float*)d_in[5];
    const float* w2a = (const float*)d_in[6],  *b2a = (const float*)d_in[7];
    const float* w2b = (const float*)d_in[8],  *b2b = (const float*)d_in[9];
    const float* w3a = (const float*)d_in[10], *b3a = (const float*)d_in[11];
    const float* w3b = (const float*)d_in[12], *b3b = (const float*)d_in[13];
    const float* rp1 = (const float*)d_in[14], *rp1b = (const float*)d_in[15];
    const float* rp2 = (const float*)d_in[16], *rp2b = (const float*)d_in[17];
    const float* rp3 = (const float*)d_in[18], *rp3b = (const float*)d_in[19];
    const float* g1 = (const float*)d_in[20], *be1 = (const float*)d_in[21];
    const float* g2 = (const float*)d_in[22], *be2 = (const float*)d_in[23];
    const float* g3 = (const float*)d_in[24], *be3 = (const float*)d_in[25];

    char* ws = (char*)d_ws;
    size_t off = 0;
    auto alloc = [&](size_t n) { char* p = ws + off; off += (n + 255) & ~(size_t)255; return p; };
    unsigned short* w1aT = (unsigned short*)alloc((size_t)128 * 256 * 2);
    unsigned short* w1bT = (unsigned short*)alloc((size_t)256 * 256 * 2);
    unsigned short* w2aT = (unsigned short*)alloc((size_t)256 * 512 * 2);
    unsigned short* w2bT = (unsigned short*)alloc((size_t)512 * 512 * 2);
    unsigned short* w3aT = (unsigned short*)alloc((size_t)512 * 1024 * 2);
    unsigned short* w3bT = (unsigned short*)alloc((size_t)1024 * 1024 * 2);
    unsigned short* rp1T = (unsigned short*)alloc((size_t)128 * 256 * 2);
    unsigned short* rp2T = (unsigned short*)alloc((size_t)256 * 512 * 2);
    unsigned short* rp3T = (unsigned short*)alloc((size_t)512 * 1024 * 2);
    unsigned short* hA  = (unsigned short*)alloc((size_t)M_PAD * 512 * 2);
    unsigned short* hB  = (unsigned short*)alloc((size_t)M_PAD * 512 * 2);
    unsigned short* zin = (unsigned short*)alloc((size_t)M_PAD * 512 * 2);
    unsigned short* z1  = (unsigned short*)alloc((size_t)M_PAD * 1024 * 2);
    float* resb = (float*)alloc((size_t)M_PAD * 1024 * 4);
    int* deg     = (int*)alloc((size_t)NN * 4);
    int* row_ptr = (int*)alloc((size_t)NN * 4);
    int* cursor  = (int*)alloc((size_t)NN * 4);
    int* colv    = (int*)alloc((size_t)NE * 4);
    (void)ws_size; (void)in_sizes; (void)n_in; (void)out_size;

    // ---- CSR build (shared by all 3 blocks) ----
    zero_k<<<cdiv(NN, 256), 256, 0, stream>>>(deg, NN);
    hist_k<<<cdiv(NE, 256), 256, 0, stream>>>(ei, deg);
    scan_k<<<1, 1024, 0, stream>>>(deg, row_ptr, cursor);
    build_col_k<<<cdiv(NE, 256), 256, 0, stream>>>(ei, cursor, colv);

    // ---- weights -> bf16 transposed (N x K) ----
    wt_k<<<cdiv(128 * 256, 256), 256, 0, stream>>>(w1a, w1aT, 128, 256);
    wt_k<<<cdiv(256 * 256, 256), 256, 0, stream>>>(w1b, w1bT, 256, 256);
    wt_k<<<cdiv(256 * 512, 256), 256, 0, stream>>>(w2a, w2aT, 256, 512);
    wt_k<<<cdiv(512 * 512, 256), 256, 0, stream>>>(w2b, w2bT, 512, 512);
    wt_k<<<cdiv(512 * 1024, 256), 256, 0, stream>>>(w3a, w3aT, 512, 1024);
    wt_k<<<cdiv(1024 * 1024, 256), 256, 0, stream>>>(w3b, w3bT, 1024, 1024);
    wt_k<<<cdiv(128 * 256, 256), 256, 0, stream>>>(rp1, rp1T, 128, 256);
    wt_k<<<cdiv(256 * 512, 256), 256, 0, stream>>>(rp2, rp2T, 256, 512);
    wt_k<<<cdiv(512 * 1024, 256), 256, 0, stream>>>(rp3, rp3T, 512, 1024);

    // x -> bf16
    f32_to_bf16_k<<<cdiv((long)NN * 128 / 4, 256), 256, 0, stream>>>(x, hA, (long)NN * 128 / 4);

    // ---- block 1: Din=128, Dout=256, h = hA ----
    agg_gather_k<128><<<cdiv(NN, 4), 256, 0, stream>>>(hA, row_ptr, deg, colv, zin);
    gemm_relu_k<128, 256><<<dim3(2, 391), 256, 0, stream>>>(zin, w1aT, b1a, z1, NN);
    gemm_fused_k<256, 128, 256><<<dim3(2, 391), 256, 0, stream>>>(z1, w1bT, b1b, hA, rp1T, rp1b, resb, NN);
    ln_k<256, true><<<NN, 256, 0, stream>>>(resb, g1, be1, hB, nullptr);

    // ---- block 2: Din=256, Dout=512, h = hB ----
    agg_gather_k<256><<<cdiv(NN, 4), 256, 0, stream>>>(hB, row_ptr, deg, colv, zin);
    gemm_relu_k<256, 512><<<dim3(4, 391), 256, 0, stream>>>(zin, w2aT, b2a, z1, NN);
    gemm_fused_k<512, 256, 512><<<dim3(4, 391), 256, 0, stream>>>(z1, w2bT, b2b, hB, rp2T, rp2b, resb, NN);
    ln_k<512, true><<<NN, 256, 0, stream>>>(resb, g2, be2, hA, nullptr);

    // ---- block 3: Din=512, Dout=1024, h = hA ----
    agg_gather_k<512><<<cdiv(NN, 4), 256, 0, stream>>>(hA, row_ptr, deg, colv, zin);
    gemm_relu_k<512, 1024><<<dim3(8, 391), 256, 0, stream>>>(zin, w3aT, b3a, z1, NN);
    gemm_fused_k<1024, 512, 1024><<<dim3(8, 391), 256, 0, stream>>>(z1, w3bT, b3b, hA, rp3T, rp3b, resb, NN);
    ln_k<1024, false><<<NN, 256, 0, stream>>>(resb, g3, be3, nullptr, (float*)d_out);
}